// Round 1
// baseline (15528.906 us; speedup 1.0000x reference)
//
#include <hip/hip_runtime.h>
#include <hip/hip_bf16.h>

#define HDIM 512
#define BATCH 32
#define SEQ 128
#define VOCAB 16384
#define NBLK_L 256   // blocks in logits kernel (each covers 64 vocab rows)

static __device__ __forceinline__ float4 ld4(const float* p) {
    return *reinterpret_cast<const float4*>(p);
}
static __device__ __forceinline__ float dot4(float4 a, float4 b) {
    return a.x*b.x + a.y*b.y + a.z*b.z + a.w*b.w;
}

// ---------------- zero init (h0 = 0) ----------------
__global__ __launch_bounds__(256) void zero_kernel(float* __restrict__ p, int n) {
    int i = blockIdx.x * 256 + threadIdx.x;
    if (i < n) p[i] = 0.f;
}

// ---------------- GRU step (encoder or decoder) ----------------
// grid: 128 blocks x 256 threads. Block owns j-slice of 4 gate-triples.
// wave w (0..3) handles j = blockIdx*4 + w for ALL 32 batch rows:
//   lane = kh*32 + b  (kh = k-half of 512, b = batch row)
// Each lane: partial dots over its 256-k half for gates r,z,n (x-part and
// h-part; n kept split since r multiplies only the h-part). shfl_xor(32)
// combines the two halves.
__global__ __launch_bounds__(256) void gru_step(
    const float* __restrict__ h_in, float* __restrict__ h_out,
    const float* __restrict__ Wih, const float* __restrict__ Whh,
    const float* __restrict__ bih, const float* __restrict__ bhh,
    const float* __restrict__ emb,
    const int* __restrict__ enc_tokens,   // non-null => encoder mode
    int t,
    const float* __restrict__ amax_val, const int* __restrict__ amax_idx)
{
    __shared__ int tok_s[BATCH];
    __shared__ float red_v[BATCH][8];
    __shared__ int   red_i[BATCH][8];

    const int tid = threadIdx.x;

    // ---- resolve tokens for all 32 rows ----
    if (enc_tokens != nullptr) {
        if (tid < BATCH) tok_s[tid] = enc_tokens[tid * SEQ + t];
    } else if (t == 0) {
        if (tid < BATCH) tok_s[tid] = 0;   // SOS
    } else {
        // finalize argmax from 256 per-block partials (first-index ties)
        int b = tid >> 3, c = tid & 7;
        const float* av = amax_val + b * NBLK_L + c * 32;
        const int*   ai = amax_idx + b * NBLK_L + c * 32;
        float bv = av[0]; int bi = ai[0];
        #pragma unroll 4
        for (int k = 1; k < 32; ++k) {
            float v = av[k]; int ix = ai[k];
            if (v > bv || (v == bv && ix < bi)) { bv = v; bi = ix; }
        }
        red_v[b][c] = bv; red_i[b][c] = bi;
        __syncthreads();
        if (tid < BATCH) {
            float bv2 = red_v[tid][0]; int bi2 = red_i[tid][0];
            #pragma unroll
            for (int c2 = 1; c2 < 8; ++c2) {
                float v = red_v[tid][c2]; int ix = red_i[tid][c2];
                if (v > bv2 || (v == bv2 && ix < bi2)) { bv2 = v; bi2 = ix; }
            }
            tok_s[tid] = bi2;
        }
    }
    __syncthreads();

    // ---- GRU compute ----
    const int wave = tid >> 6;        // 0..3
    const int lane = tid & 63;
    const int kh   = lane >> 5;       // 0..1 : k-half
    const int b    = lane & 31;       // batch row
    const int j    = blockIdx.x * 4 + wave;   // 0..511

    const int tok = tok_s[b];
    const float* xrow = emb  + (size_t)tok * HDIM + kh * 256;
    const float* hrow = h_in + b * HDIM + kh * 256;
    const float* wir = Wih + (size_t)(0*HDIM + j) * HDIM + kh * 256;
    const float* wiz = Wih + (size_t)(1*HDIM + j) * HDIM + kh * 256;
    const float* win = Wih + (size_t)(2*HDIM + j) * HDIM + kh * 256;
    const float* whr = Whh + (size_t)(0*HDIM + j) * HDIM + kh * 256;
    const float* whz = Whh + (size_t)(1*HDIM + j) * HDIM + kh * 256;
    const float* whn = Whh + (size_t)(2*HDIM + j) * HDIM + kh * 256;

    float pr = 0.f, pz = 0.f, pxn = 0.f, phn = 0.f;
    #pragma unroll 4
    for (int k4 = 0; k4 < 64; ++k4) {
        float4 x4 = ld4(xrow + k4*4);
        float4 h4 = ld4(hrow + k4*4);
        pr  += dot4(x4, ld4(wir + k4*4)) + dot4(h4, ld4(whr + k4*4));
        pz  += dot4(x4, ld4(wiz + k4*4)) + dot4(h4, ld4(whz + k4*4));
        pxn += dot4(x4, ld4(win + k4*4));
        phn += dot4(h4, ld4(whn + k4*4));
    }
    // combine the two k-halves
    pr  += __shfl_xor(pr, 32);
    pz  += __shfl_xor(pz, 32);
    pxn += __shfl_xor(pxn, 32);
    phn += __shfl_xor(phn, 32);

    if (kh == 0) {
        float r = 1.f / (1.f + expf(-(pr + bih[j]        + bhh[j])));
        float z = 1.f / (1.f + expf(-(pz + bih[HDIM+j]   + bhh[HDIM+j])));
        float n = tanhf(pxn + bih[2*HDIM+j] + r * (phn + bhh[2*HDIM+j]));
        float hprev = h_in[b * HDIM + j];
        h_out[b * HDIM + j] = (1.f - z) * n + z * hprev;
    }
}

// ---------------- decoder logits + argmax partials ----------------
// grid: 256 blocks x 256 threads. Block covers 64 vocab rows, all 32 batch.
// thread: vloc = tid&63 (vocab row), ks = tid>>6 (k-quarter of 512).
// acc[32] over batch; LDS combine of 4 k-partials; wave argmax per batch row.
__global__ __launch_bounds__(256) void logits_kernel(
    const float* __restrict__ h, const float* __restrict__ outW,
    const float* __restrict__ outb, float* __restrict__ out,
    int t, float* __restrict__ amax_val, int* __restrict__ amax_idx)
{
    __shared__ float part[4][64][33];   // [ks][vloc][b], padded

    const int tid  = threadIdx.x;
    const int vloc = tid & 63;
    const int ks   = __builtin_amdgcn_readfirstlane(tid >> 6);  // wave id, uniform
    const int v    = blockIdx.x * 64 + vloc;

    float acc[BATCH];
    #pragma unroll
    for (int b = 0; b < BATCH; ++b) acc[b] = 0.f;

    const float* wrow = outW + (size_t)v * HDIM + ks * 128;
    const float* hq   = h + ks * 128;

    for (int k4 = 0; k4 < 32; ++k4) {
        float4 w4 = ld4(wrow + k4*4);
        #pragma unroll
        for (int b = 0; b < BATCH; ++b) {
            float4 h4 = ld4(hq + b * HDIM + k4*4);   // uniform addr -> s_load
            acc[b] += dot4(w4, h4);
        }
    }

    #pragma unroll
    for (int b = 0; b < BATCH; ++b) part[ks][vloc][b] = acc[b];
    __syncthreads();

    const int bg = tid >> 6;          // 8 batch rows per wave
    const float vbias = outb[v];
    #pragma unroll
    for (int i = 0; i < 8; ++i) {
        const int b = bg * 8 + i;
        float s = part[0][vloc][b] + part[1][vloc][b]
                + part[2][vloc][b] + part[3][vloc][b] + vbias;
        out[(size_t)b * (SEQ * VOCAB) + (size_t)t * VOCAB + v] = s;

        // wave-level argmax over the 64 vocab rows (first-index ties)
        float mv = s; int mi = v;
        #pragma unroll
        for (int d = 1; d < 64; d <<= 1) {
            float ov = __shfl_xor(mv, d);
            int   oi = __shfl_xor(mi, d);
            if (ov > mv || (ov == mv && oi < mi)) { mv = ov; mi = oi; }
        }
        if (vloc == 0) {
            amax_val[b * NBLK_L + blockIdx.x] = mv;
            amax_idx[b * NBLK_L + blockIdx.x] = mi;
        }
    }
}

// ---------------- deferred log_softmax over each [16384] row ----------------
__global__ __launch_bounds__(256) void softmax_kernel(float* __restrict__ out) {
    __shared__ float redm[4];
    __shared__ float reds[4];
    const int tid = threadIdx.x;
    float* p = out + (size_t)blockIdx.x * VOCAB;

    float4 vals[16];
    float m = -3.4e38f;
    #pragma unroll
    for (int i = 0; i < 16; ++i) {
        vals[i] = ld4(p + (i * 256 + tid) * 4);
        m = fmaxf(m, fmaxf(fmaxf(vals[i].x, vals[i].y), fmaxf(vals[i].z, vals[i].w)));
    }
    #pragma unroll
    for (int d = 1; d < 64; d <<= 1) m = fmaxf(m, __shfl_xor(m, d));
    if ((tid & 63) == 0) redm[tid >> 6] = m;
    __syncthreads();
    m = fmaxf(fmaxf(redm[0], redm[1]), fmaxf(redm[2], redm[3]));

    float s = 0.f;
    #pragma unroll
    for (int i = 0; i < 16; ++i) {
        s += expf(vals[i].x - m) + expf(vals[i].y - m)
           + expf(vals[i].z - m) + expf(vals[i].w - m);
    }
    #pragma unroll
    for (int d = 1; d < 64; d <<= 1) s += __shfl_xor(s, d);
    if ((tid & 63) == 0) reds[tid >> 6] = s;
    __syncthreads();
    s = reds[0] + reds[1] + reds[2] + reds[3];

    const float lg = m + logf(s);
    #pragma unroll
    for (int i = 0; i < 16; ++i) {
        float4 r;
        r.x = vals[i].x - lg; r.y = vals[i].y - lg;
        r.z = vals[i].z - lg; r.w = vals[i].w - lg;
        *reinterpret_cast<float4*>(p + (i * 256 + tid) * 4) = r;
    }
}

// ---------------- copy final hidden ----------------
__global__ __launch_bounds__(256) void copy_kernel(const float* __restrict__ src,
                                                   float* __restrict__ dst, int n) {
    int i = blockIdx.x * 256 + threadIdx.x;
    if (i < n) dst[i] = src[i];
}

extern "C" void kernel_launch(void* const* d_in, const int* in_sizes, int n_in,
                              void* d_out, int out_size, void* d_ws, size_t ws_size,
                              hipStream_t stream) {
    const int*   input    = (const int*)  d_in[0];
    const float* enc_emb  = (const float*)d_in[1];
    const float* enc_Wih  = (const float*)d_in[2];
    const float* enc_Whh  = (const float*)d_in[3];
    const float* enc_bih  = (const float*)d_in[4];
    const float* enc_bhh  = (const float*)d_in[5];
    const float* dec_emb  = (const float*)d_in[6];
    const float* dec_Wih  = (const float*)d_in[7];
    const float* dec_Whh  = (const float*)d_in[8];
    const float* dec_bih  = (const float*)d_in[9];
    const float* dec_bhh  = (const float*)d_in[10];
    const float* out_W    = (const float*)d_in[11];
    const float* out_b    = (const float*)d_in[12];

    float* out = (float*)d_out;
    float* ws  = (float*)d_ws;

    float* hbuf[2] = { ws, ws + BATCH * HDIM };        // ping-pong hidden
    float* av = ws + 2 * BATCH * HDIM;                  // argmax partial values
    int*   ai = (int*)(av + BATCH * NBLK_L);            // argmax partial indices

    // h0 = 0
    zero_kernel<<<dim3((BATCH * HDIM + 255) / 256), dim3(256), 0, stream>>>(
        hbuf[0], BATCH * HDIM);

    // ---- encoder: 128 sequential GRU steps ----
    for (int t = 0; t < SEQ; ++t) {
        gru_step<<<dim3(128), dim3(256), 0, stream>>>(
            hbuf[t & 1], hbuf[(t + 1) & 1],
            enc_Wih, enc_Whh, enc_bih, enc_bhh,
            enc_emb, input, t, nullptr, nullptr);
    }

    // ---- decoder: 128 sequential (GRU -> logits/argmax) steps ----
    for (int t = 0; t < SEQ; ++t) {
        gru_step<<<dim3(128), dim3(256), 0, stream>>>(
            hbuf[t & 1], hbuf[(t + 1) & 1],
            dec_Wih, dec_Whh, dec_bih, dec_bhh,
            dec_emb, nullptr, t, av, ai);
        logits_kernel<<<dim3(NBLK_L), dim3(256), 0, stream>>>(
            hbuf[(t + 1) & 1], out_W, out_b, out, t, av, ai);
    }

    // ---- deferred log_softmax over all B*SEQ rows ----
    softmax_kernel<<<dim3(BATCH * SEQ), dim3(256), 0, stream>>>(out);

    // ---- final decoder hidden -> d_out tail ----
    copy_kernel<<<dim3((BATCH * HDIM + 255) / 256), dim3(256), 0, stream>>>(
        hbuf[0], out + (size_t)BATCH * SEQ * VOCAB, BATCH * HDIM);
}